// Round 3
// baseline (184.657 us; speedup 1.0000x reference)
//
#include <hip/hip_runtime.h>
#include <cstdint>

// Dynamic_MLP_C: fused bf16-MFMA implementation.
//
// Reformulation: x[t,o] = sum_k A[t,k] * B[k,o],  k = j*64+i  (K = 4160)
//   A[t, j*64+i] = w21[t,j] * w12[t,i]  (rank-1), bias rows A[t,4096+i]=w12[t,i].
// Re-association: x[t,o] = sum_j w21[t,j] * (w12[t,:] @ B_j)[o]
//   -> A-fragment = CONSTANT w12 regs; per j: 2 MFMAs -> m; acc += w21[t,j]*m.
//
// History:
//  R9  (512 blk, 64 tok, 2 w/SIMD, 272 MB L2): main ~33us.
//  R12 (1024 blk, 32 tok, 4 w/SIMD, 545 MB L2): main ~33us. Total 114.7.
//  R13 FAILED: cooperative fusion -> 320us (grid.sync spin + regalloc collapse).
//  R14 NEUTRAL-NEG: K-start stagger -> 117.3. L2-contention theory dead; stagger
//      also broke co-resident blocks' L1 sharing of identical B streams.
//  => R9==R12 despite 2x TLP and 2x traffic: the invariant is the PER-WAVE
//     serial path of 32 dependent chunk-steps (~2475 cyc/step, ~6x issue cost).
//  R15 (this round): K-SPLIT. 512 blocks x 8 waves (512 thr), 64 tokens/block.
//     wave = (kh = K-half, og = o-group). Each wave: 16 chunks, mf=4.
//     Partner waves (kh=0/1, same og) combine acc via LDS. Halves the serial
//     chunk path AND total B traffic (272 MB) at unchanged occupancy
//     (2 blk/CU x 8 waves = 4 w/SIMD); restores lockstep B-walk for L1 reuse.

typedef __bf16 bf16x4 __attribute__((ext_vector_type(4)));
typedef __bf16 bf16x8 __attribute__((ext_vector_type(8)));
typedef float  f32x4  __attribute__((ext_vector_type(4)));

#define MFMA16(A, B, C) __builtin_amdgcn_mfma_f32_16x16x32_bf16(A, B, C, 0, 0, 0)

// workspace element offsets (bf16 elements)
#define OFF_BT22 0         // K=4160 grouped layout, 266240 elems
#define OFF_W11  266240    // K=128,  8192 (frag layout)
#define OFF_W21  274432    // K=128,  8192
#define OFF_W12  282624    // K=64,   4096
#define OFF_W3   286720    // K=64,   4096

// prep: [64 k x 64 o] fp32 tile -> bf16.
//  W22/b22 tiles: grouped layout ws[((o>>4)*520 + k8)*128 + (o&15)*8 + (k&7)]
//  small weights: frag layout    ws[base + (k>>3)*512 + o*8 + (k&7)]
__global__ __launch_bounds__(256) void prep_kernel(
    const float* __restrict__ W22, const float* __restrict__ b22,
    const float* __restrict__ W11, const float* __restrict__ W21,
    const float* __restrict__ W12, const float* __restrict__ W3,
    __bf16* __restrict__ ws)
{
    __shared__ __bf16 T[64][72];
    const int b = blockIdx.x, tid = threadIdx.x;
    const float* src; long base = 0;
    if (b < 64)       { src = W22 + b * 4096; }
    else if (b == 64) { src = b22; }
    else if (b < 67)  { src = W11 + (b - 65) * 4096; base = OFF_W11 + (b - 65) * 4096; }
    else if (b < 69)  { src = W21 + (b - 67) * 4096; base = OFF_W21 + (b - 67) * 4096; }
    else if (b == 69) { src = W12;                   base = OFF_W12; }
    else              { src = W3;                    base = OFF_W3; }
    #pragma unroll
    for (int it = 0; it < 4; ++it) {
        int u = it * 1024 + tid * 4;
        int r = u >> 6, c = u & 63;
        const float4 v = *(const float4*)(src + u);
        T[r][c] = (__bf16)v.x; T[r][c + 1] = (__bf16)v.y;
        T[r][c + 2] = (__bf16)v.z; T[r][c + 3] = (__bf16)v.w;
    }
    __syncthreads();
    #pragma unroll
    for (int it = 0; it < 2; ++it) {
        int item = it * 256 + tid;
        int q = item >> 6, o = item & 63;
        bf16x8 pk;
        #pragma unroll
        for (int kj = 0; kj < 8; ++kj) pk[kj] = T[q * 8 + kj][o];
        long dstE;
        if (b <= 64) {
            int k8 = (b == 64 ? 512 : b * 8) + q;
            dstE = OFF_BT22 + ((long)(o >> 4) * 520 + k8) * 128 + (o & 15) * 8;
        } else {
            dstE = base + q * 512 + o * 8;
        }
        *(bf16x8*)(ws + dstE) = pk;
    }
}

// ---- register chunk-buffer machinery: named registers, token-pasted ----
#define LOADCH(buf, c) do {                                          \
    buf##_0 = *(const bf16x8*)(Bw + ((c)*16 +  0) * 128);            \
    buf##_1 = *(const bf16x8*)(Bw + ((c)*16 +  4) * 128);            \
    buf##_2 = *(const bf16x8*)(Bw + ((c)*16 +  8) * 128);            \
    buf##_3 = *(const bf16x8*)(Bw + ((c)*16 + 12) * 128);            \
} while (0)

// mf = 4 (64 tokens per wave), j is LOCAL to this wave's K-half.
#define COMPUTE_J(b0, b1, j) do {                                    \
    f32x4 w4[4];                                                     \
    _Pragma("unroll")                                                \
    for (int mf = 0; mf < 4; ++mf) {                                 \
        bf16x4 wv4 = *(const bf16x4*)(w21Tk + (j)*72 + mf*16 + quad*4);\
        w4[mf] = __builtin_convertvector(wv4, f32x4);                \
    }                                                                \
    _Pragma("unroll")                                                \
    for (int mf = 0; mf < 4; ++mf) {                                 \
        f32x4 fz = {};                                               \
        f32x4 m = MFMA16(a12[mf][0], b0, fz);                        \
        m       = MFMA16(a12[mf][1], b1, m);                         \
        _Pragma("unroll")                                            \
        for (int r = 0; r < 4; ++r)                                  \
            acc[mf][r] = fmaf(w4[mf][r], m[r], acc[mf][r]);          \
    }                                                                \
} while (0)

#define COMPUTE(buf, c) do {                                         \
    COMPUTE_J(buf##_0, buf##_1, (c)*2);                              \
    COMPUTE_J(buf##_2, buf##_3, (c)*2 + 1);                          \
} while (0)

__global__ __launch_bounds__(512, 4) void main_kernel(
    const float* __restrict__ img, const float* __restrict__ loc,
    const float* __restrict__ b11, const float* __restrict__ b12,
    const float* __restrict__ b21, const float* __restrict__ ln_g,
    const float* __restrict__ ln_b, const float* __restrict__ b3,
    const __bf16* __restrict__ ws, float* __restrict__ out)
{
    // LDS carve (47104 B, 2 blocks/CU = 94 KB):
    //  [0,17408)       catL [64][136] bf16    (reused as combL [4][64][17] f32)
    //  [17408,26624)   w11L [64][72]  bf16    (reused as xL in P4/P5)
    //  [26624,35840)   w12L [64][72]  bf16
    //  [35840,45056)   w21T [64 j][72 t] bf16 (transposed; 2-way max on writes)
    //  [45056,47104)   ps   [64][4] float2    (LN cross-og partials)
    __shared__ __align__(1024) char smem[47104];
    __bf16* catL = (__bf16*)smem;
    __bf16* w11L = (__bf16*)(smem + 17408);
    __bf16* w12L = (__bf16*)(smem + 26624);
    __bf16* w21T = (__bf16*)(smem + 35840);
    float2* ps   = (float2*)(smem + 45056);
    float*  combL = (float*)smem;   // [4 og][64 t][17] = 17408 B exactly
    __bf16* xL   = w11L;

    const int tid  = threadIdx.x;
    const int wv   = tid >> 6;      // 0..7
    const int og   = wv & 3;        // o-column group (16 cols)
    const int kh   = wv >> 2;       // K-half (0: chunks 0-15, 1: 16-31)
    const int lane = tid & 63;
    const int ln   = lane & 15;     // A-row / C-col / B-col lane index
    const int quad = lane >> 4;     // k-quad / C-row group
    const int ob   = og * 16;       // this wave's 16 o-cols
    const long tb  = (long)blockIdx.x * 64;

    const __bf16* Bt22  = ws + OFF_BT22;
    const __bf16* W11bt = ws + OFF_W11;
    const __bf16* W21bt = ws + OFF_W21;
    const __bf16* W12bt = ws + OFF_W12;
    const __bf16* W3bt  = ws + OFF_W3;

    // ---------- P0: stage cat = [img | loc] as bf16 (64 tokens) ----------
    {
        const float* srcs[2] = {img, loc};
        #pragma unroll
        for (int s = 0; s < 2; ++s) {
            const float* src = srcs[s] + tb * 64;
            #pragma unroll
            for (int it = 0; it < 2; ++it) {
                int u = (it * 512 + tid) * 4;         // 0..4092
                int t = u >> 6, c = u & 63;
                const float4 v = *(const float4*)(src + u);
                bf16x4 pk = {(__bf16)v.x, (__bf16)v.y, (__bf16)v.z, (__bf16)v.w};
                *(bf16x4*)(catL + t * 136 + s * 64 + c) = pk;
            }
        }
    }
    __syncthreads();

    // ---------- P1: waves 0-3 -> w11 cols og*16..+16 (A-layout);
    //               waves 4-7 -> w21 cols og*16..+16 (TRANSPOSED) ----------
    {
        const int isW21 = kh;
        const __bf16* Wbt = isW21 ? W21bt : W11bt;
        const float* bsel = isW21 ? b21 : b11;
        f32x4 a1[4] = {};
        #pragma unroll
        for (int kb = 0; kb < 4; ++kb) {
            bf16x8 bw = *(const bf16x8*)(Wbt + ((kb*4 + quad)*64 + ob + ln)*8);
            #pragma unroll
            for (int mf = 0; mf < 4; ++mf) {
                bf16x8 af = *(const bf16x8*)(catL + (mf*16 + ln)*136 + kb*32 + quad*8);
                a1[mf] = MFMA16(af, bw, a1[mf]);
            }
        }
        float cb = bsel[ob + ln];
        if (!isW21) {
            #pragma unroll
            for (int mf = 0; mf < 4; ++mf)
                #pragma unroll
                for (int r = 0; r < 4; ++r) {
                    int t = mf*16 + quad*4 + r;
                    float v = a1[mf][r] + cb; v = v > 0.f ? v : 0.f;
                    w11L[t*72 + ob + ln] = (__bf16)v;
                }
        } else {
            #pragma unroll
            for (int mf = 0; mf < 4; ++mf) {
                bf16x4 pk;
                #pragma unroll
                for (int r = 0; r < 4; ++r) {
                    float v = a1[mf][r] + cb; v = v > 0.f ? v : 0.f;
                    pk[r] = (__bf16)v;
                }
                *(bf16x4*)(w21T + (ob + ln)*72 + mf*16 + quad*4) = pk;
            }
        }
    }
    __syncthreads();

    // ---------- P2: w12 = w11@W12 + b12 (no relu); wave (kh,og) -> 32t x 16o ----------
    {
        float c12 = b12[ob + ln];
        f32x4 a12c[2] = {};
        #pragma unroll
        for (int kb = 0; kb < 2; ++kb) {
            bf16x8 bw = *(const bf16x8*)(W12bt + ((kb*4 + quad)*64 + ob + ln)*8);
            #pragma unroll
            for (int mf = 0; mf < 2; ++mf) {
                bf16x8 af = *(const bf16x8*)(w11L + (kh*32 + mf*16 + ln)*72 + kb*32 + quad*8);
                a12c[mf] = MFMA16(af, bw, a12c[mf]);
            }
        }
        #pragma unroll
        for (int mf = 0; mf < 2; ++mf)
            #pragma unroll
            for (int r = 0; r < 4; ++r) {
                int t = kh*32 + mf*16 + quad*4 + r;
                w12L[t*72 + ob + ln] = (__bf16)(a12c[mf][r] + c12);
            }
    }
    __syncthreads();

    // w12 A-fragments: constant MFMA A-operand for the whole K-loop (and the
    // bias-block A directly). Full 64-k rows per token, 64 tokens/wave (mf=4).
    bf16x8 a12[4][2];
    #pragma unroll
    for (int mf = 0; mf < 4; ++mf)
        #pragma unroll
        for (int sub = 0; sub < 2; ++sub)
            a12[mf][sub] = *(const bf16x8*)(w12L + (mf*16 + ln)*72 + sub*32 + quad*8);

    // ---------- P3: barrier-free K-HALF loop, named VGPR double-buffer ----------
    // Wave (kh,og): 16 chunks of its K-half, lockstep from local chunk 0.
    const __bf16* BwBase = Bt22 + ((long)og * 520 + quad) * 128 + ln * 8;
    const __bf16* Bw     = BwBase + (long)kh * 32768;   // kh*16 chunks * 2048 elems
    const __bf16* w21Tk  = w21T + kh * 32 * 72;         // local j base

    bf16x8 B0_0, B0_1, B0_2, B0_3;
    bf16x8 B1_0, B1_1, B1_2, B1_3;

    f32x4 acc[4] = {};
    LOADCH(B0, 0);
    #pragma unroll 1
    for (int cc = 0; cc < 16; cc += 2) {
        LOADCH(B1, cc + 1);
        COMPUTE(B0, cc);
        if (cc + 2 < 16) LOADCH(B0, cc + 2);
        COMPUTE(B1, cc + 1);
    }
    // bias rows (k8=512..519): A = w12 directly, weight 1. kh=1 only.
    if (kh == 1) {
        bf16x8 bb0 = *(const bf16x8*)(BwBase + (512 + 0) * 128);
        bf16x8 bb1 = *(const bf16x8*)(BwBase + (512 + 4) * 128);
        #pragma unroll
        for (int mf = 0; mf < 4; ++mf) {
            acc[mf] = MFMA16(a12[mf][0], bb0, acc[mf]);
            acc[mf] = MFMA16(a12[mf][1], bb1, acc[mf]);
        }
    }

    // ---------- P3b: combine K-halves (kh=1 -> LDS -> kh=0 adds) ----------
    // combL stride 17 floats per t (2-way max bank aliasing).
    if (kh == 1) {
        #pragma unroll
        for (int mf = 0; mf < 4; ++mf)
            #pragma unroll
            for (int r = 0; r < 4; ++r) {
                int t = mf*16 + quad*4 + r;
                combL[og*1088 + t*17 + ln] = acc[mf][r];
            }
    }
    __syncthreads();

    // ---------- P4: LayerNorm(64) + relu (kh=0 waves own full acc) ----------
    if (kh == 0) {
        #pragma unroll
        for (int mf = 0; mf < 4; ++mf)
            #pragma unroll
            for (int r = 0; r < 4; ++r) {
                int t = mf*16 + quad*4 + r;
                acc[mf][r] += combL[og*1088 + t*17 + ln];
                float v = acc[mf][r];
                float s1 = v, s2 = v*v;
                #pragma unroll
                for (int d = 1; d < 16; d <<= 1) {   // reduce this quad's 16 lanes
                    s1 += __shfl_xor(s1, d, 64);
                    s2 += __shfl_xor(s2, d, 64);
                }
                if (ln == 0) ps[t*4 + og] = make_float2(s1, s2);
            }
    }
    __syncthreads();

    if (kh == 0) {
        float gv = ln_g[ob + ln], bv = ln_b[ob + ln];
        #pragma unroll
        for (int mf = 0; mf < 4; ++mf)
            #pragma unroll
            for (int r = 0; r < 4; ++r) {
                int t = mf*16 + quad*4 + r;
                float2 p0 = ps[t*4], p1 = ps[t*4 + 1], p2 = ps[t*4 + 2], p3 = ps[t*4 + 3];
                float mean = (p0.x + p1.x + p2.x + p3.x) * 0.015625f;
                float var  = (p0.y + p1.y + p2.y + p3.y) * 0.015625f - mean * mean;
                float inv  = rsqrtf(var + 1e-5f);
                float v = (acc[mf][r] - mean) * inv * gv + bv;
                v = v > 0.f ? v : 0.f;
                xL[t*72 + ob + ln] = (__bf16)v;
            }
    }
    __syncthreads();

    // ---------- P5: out = x @ W3 + b3 (all 8 waves: (kh,og) -> 32t x 16o) ----------
    {
        float b3v = b3[ob + ln];
        f32x4 a3[2] = {};
        #pragma unroll
        for (int kb = 0; kb < 2; ++kb) {
            bf16x8 bfr = *(const bf16x8*)(W3bt + ((kb*4 + quad)*64 + ob + ln)*8);
            #pragma unroll
            for (int mf = 0; mf < 2; ++mf) {
                bf16x8 af = *(const bf16x8*)(xL + (kh*32 + mf*16 + ln)*72 + kb*32 + quad*8);
                a3[mf] = MFMA16(af, bfr, a3[mf]);
            }
        }
        #pragma unroll
        for (int mf = 0; mf < 2; ++mf)
            #pragma unroll
            for (int r = 0; r < 4; ++r) {
                long t = tb + kh*32 + mf*16 + quad*4 + r;
                out[t*64 + ob + ln] = a3[mf][r] + b3v;
            }
    }
}

extern "C" void kernel_launch(void* const* d_in, const int* in_sizes, int n_in,
                              void* d_out, int out_size, void* d_ws, size_t ws_size,
                              hipStream_t stream)
{
    const float* img  = (const float*)d_in[0];
    const float* loc  = (const float*)d_in[1];
    const float* W11  = (const float*)d_in[2];
    const float* b11  = (const float*)d_in[3];
    const float* W12  = (const float*)d_in[4];
    const float* b12  = (const float*)d_in[5];
    const float* W21  = (const float*)d_in[6];
    const float* b21  = (const float*)d_in[7];
    const float* W22  = (const float*)d_in[8];
    const float* b22  = (const float*)d_in[9];
    const float* ln_g = (const float*)d_in[10];
    const float* ln_b = (const float*)d_in[11];
    const float* W3   = (const float*)d_in[12];
    const float* b3   = (const float*)d_in[13];
    __bf16* ws = (__bf16*)d_ws;
    float*  o  = (float*)d_out;

    prep_kernel<<<71, 256, 0, stream>>>(W22, b22, W11, W21, W12, W3, ws);
    main_kernel<<<512, 512, 0, stream>>>(img, loc, b11, b12, b21, ln_g, ln_b, b3, ws, o);
}

// Round 4
// 114.410 us; speedup vs baseline: 1.6140x; 1.6140x over previous
//
#include <hip/hip_runtime.h>
#include <cstdint>

// Dynamic_MLP_C: fused bf16-MFMA implementation.
//
// Reformulation: x[t,o] = sum_k A[t,k] * B[k,o],  k = j*64+i  (K = 4160)
//   A[t, j*64+i] = w21[t,j] * w12[t,i]  (rank-1), bias rows A[t,4096+i]=w12[t,i].
// Re-association: x[t,o] = sum_j w21[t,j] * (w12[t,:] @ B_j)[o]
//   -> A-fragment = CONSTANT w12 regs; per j: 2 MFMAs -> m; acc += w21[t,j]*m.
//
// History:
//  R9  (512 blk, 64 tok, 2 w/SIMD): main ~33us.
//  R12 (1024 blk, 32 tok, 4 w/SIMD): main ~33us. Total 114.7us == VERIFIED BEST.
//  R13 FAILED (320us): cooperative prep+main fusion. grid.sync spin + all-thread
//      threadfence, and merged-kernel regalloc collapsed to 60 VGPR.
//  R14 NEUTRAL-NEG (117.3us): K-start stagger. L2-contention theory dead; also
//      broke co-resident blocks' L1 sharing of the identical B stream.
//  R15 FAILED (184.7us): K-split 8-wave mf=4. VGPR_Count=64 + scratch spills
//      (WRITE_SIZE 77MB): regalloc refused the mf=4 named double-buffer.
//  R16 (this round): REVERT to the exact R12 code. The 33us K-loop has resisted
//      TLP (R12), prefetch depth (R10), stagger (R14), and K-split (R15); the
//      codegen holding it (named-VGPR dbuf, ~90 VGPR, no spill) only exists in
//      THIS shape. Window: ~42us harness ws-poison fill (79% HBM, untouchable)
//      + ~38us kernels + ~30us dispatch gaps.

typedef __bf16 bf16x4 __attribute__((ext_vector_type(4)));
typedef __bf16 bf16x8 __attribute__((ext_vector_type(8)));
typedef float  f32x4  __attribute__((ext_vector_type(4)));

#define MFMA16(A, B, C) __builtin_amdgcn_mfma_f32_16x16x32_bf16(A, B, C, 0, 0, 0)

// workspace element offsets (bf16 elements)
#define OFF_BT22 0         // K=4160 grouped layout, 266240 elems
#define OFF_W11  266240    // K=128,  8192 (frag layout)
#define OFF_W21  274432    // K=128,  8192
#define OFF_W12  282624    // K=64,   4096
#define OFF_W3   286720    // K=64,   4096

// prep: [64 k x 64 o] fp32 tile -> bf16.
//  W22/b22 tiles: grouped layout ws[((o>>4)*520 + k8)*128 + (o&15)*8 + (k&7)]
//  small weights: frag layout    ws[base + (k>>3)*512 + o*8 + (k&7)]
__global__ __launch_bounds__(256) void prep_kernel(
    const float* __restrict__ W22, const float* __restrict__ b22,
    const float* __restrict__ W11, const float* __restrict__ W21,
    const float* __restrict__ W12, const float* __restrict__ W3,
    __bf16* __restrict__ ws)
{
    __shared__ __bf16 T[64][72];
    const int b = blockIdx.x, tid = threadIdx.x;
    const float* src; long base = 0;
    if (b < 64)       { src = W22 + b * 4096; }
    else if (b == 64) { src = b22; }
    else if (b < 67)  { src = W11 + (b - 65) * 4096; base = OFF_W11 + (b - 65) * 4096; }
    else if (b < 69)  { src = W21 + (b - 67) * 4096; base = OFF_W21 + (b - 67) * 4096; }
    else if (b == 69) { src = W12;                   base = OFF_W12; }
    else              { src = W3;                    base = OFF_W3; }
    #pragma unroll
    for (int it = 0; it < 4; ++it) {
        int u = it * 1024 + tid * 4;
        int r = u >> 6, c = u & 63;
        const float4 v = *(const float4*)(src + u);
        T[r][c] = (__bf16)v.x; T[r][c + 1] = (__bf16)v.y;
        T[r][c + 2] = (__bf16)v.z; T[r][c + 3] = (__bf16)v.w;
    }
    __syncthreads();
    #pragma unroll
    for (int it = 0; it < 2; ++it) {
        int item = it * 256 + tid;
        int q = item >> 6, o = item & 63;
        bf16x8 pk;
        #pragma unroll
        for (int kj = 0; kj < 8; ++kj) pk[kj] = T[q * 8 + kj][o];
        long dstE;
        if (b <= 64) {
            int k8 = (b == 64 ? 512 : b * 8) + q;
            dstE = OFF_BT22 + ((long)(o >> 4) * 520 + k8) * 128 + (o & 15) * 8;
        } else {
            dstE = base + q * 512 + o * 8;
        }
        *(bf16x8*)(ws + dstE) = pk;
    }
}

// ---- register chunk-buffer machinery: named registers, token-pasted ----
#define LOADCH(buf, c) do {                                          \
    buf##_0 = *(const bf16x8*)(Bw + ((c)*16 +  0) * 128);            \
    buf##_1 = *(const bf16x8*)(Bw + ((c)*16 +  4) * 128);            \
    buf##_2 = *(const bf16x8*)(Bw + ((c)*16 +  8) * 128);            \
    buf##_3 = *(const bf16x8*)(Bw + ((c)*16 + 12) * 128);            \
} while (0)

#define COMPUTE_J(b0, b1, j) do {                                    \
    f32x4 w4[2];                                                     \
    _Pragma("unroll")                                                \
    for (int mf = 0; mf < 2; ++mf) {                                 \
        bf16x4 wv4 = *(const bf16x4*)(w21T + (j)*36 + mf*16 + quad*4);\
        w4[mf] = __builtin_convertvector(wv4, f32x4);                \
    }                                                                \
    _Pragma("unroll")                                                \
    for (int mf = 0; mf < 2; ++mf) {                                 \
        f32x4 fz = {};                                               \
        f32x4 m = MFMA16(a12[mf][0], b0, fz);                        \
        m       = MFMA16(a12[mf][1], b1, m);                         \
        _Pragma("unroll")                                            \
        for (int r = 0; r < 4; ++r)                                  \
            acc[mf][r] = fmaf(w4[mf][r], m[r], acc[mf][r]);          \
    }                                                                \
} while (0)

#define COMPUTE(buf, c) do {                                         \
    COMPUTE_J(buf##_0, buf##_1, (c)*2);                              \
    COMPUTE_J(buf##_2, buf##_3, (c)*2 + 1);                          \
} while (0)

__global__ __launch_bounds__(256, 4) void main_kernel(
    const float* __restrict__ img, const float* __restrict__ loc,
    const float* __restrict__ b11, const float* __restrict__ b12,
    const float* __restrict__ b21, const float* __restrict__ ln_g,
    const float* __restrict__ ln_b, const float* __restrict__ b3,
    const __bf16* __restrict__ ws, float* __restrict__ out)
{
    // LDS carve (23552 B, 4 blocks/CU):
    //  [0,8704)       catL [32][136] bf16
    //  [8704,13312)   w11L [32][72]  bf16   (reused as xL in P4/P5)
    //  [13312,17920)  w12L [32][72]  bf16
    //  [17920,22528)  w21T [64 j][36 t] bf16 (transposed; <=2-way on writes)
    //  [22528,23552)  ps   [32][4] float2   (LN cross-wave partials)
    __shared__ __align__(1024) char smem[23552];
    __bf16* catL = (__bf16*)smem;
    __bf16* w11L = (__bf16*)(smem + 8704);
    __bf16* w12L = (__bf16*)(smem + 13312);
    __bf16* w21T = (__bf16*)(smem + 17920);
    float2* ps   = (float2*)(smem + 22528);
    __bf16* xL   = w11L;

    const int tid  = threadIdx.x;
    const int wv   = tid >> 6;
    const int lane = tid & 63;
    const int ln   = lane & 15;     // A-row / C-col / B-col lane index
    const int quad = lane >> 4;     // k-quad / C-row group
    const int ob   = wv * 16;       // this wave's 16 o-cols (= col-group wv)
    const long tb  = (long)blockIdx.x * 32;

    const __bf16* Bt22  = ws + OFF_BT22;
    const __bf16* W11bt = ws + OFF_W11;
    const __bf16* W21bt = ws + OFF_W21;
    const __bf16* W12bt = ws + OFF_W12;
    const __bf16* W3bt  = ws + OFF_W3;

    // ---------- P0: stage cat = [img | loc] as bf16 (32 tokens) ----------
    {
        const float* srcs[2] = {img, loc};
        #pragma unroll
        for (int s = 0; s < 2; ++s) {
            const float* src = srcs[s] + tb * 64;
            #pragma unroll
            for (int it = 0; it < 2; ++it) {
                int u = (it * 256 + tid) * 4;         // 0..2044
                int t = u >> 6, c = u & 63;
                const float4 v = *(const float4*)(src + u);
                bf16x4 pk = {(__bf16)v.x, (__bf16)v.y, (__bf16)v.z, (__bf16)v.w};
                *(bf16x4*)(catL + t * 136 + s * 64 + c) = pk;
            }
        }
    }
    __syncthreads();

    // ---------- P1: wv 0,1 -> w11 cols (wv&1)*32..+32 (A-layout);
    //               wv 2,3 -> w21 cols (wv&1)*32..+32 (TRANSPOSED) ----------
    {
        const int isW21 = wv >> 1;
        const int cb0 = (wv & 1) * 32;
        const __bf16* Wbt = isW21 ? W21bt : W11bt;
        const float* bsel = isW21 ? b21 : b11;
        f32x4 a1[2][2] = {};
        #pragma unroll
        for (int kb = 0; kb < 4; ++kb) {
            bf16x8 af[2];
            #pragma unroll
            for (int mf = 0; mf < 2; ++mf)
                af[mf] = *(const bf16x8*)(catL + (mf*16 + ln)*136 + kb*32 + quad*8);
            #pragma unroll
            for (int nf = 0; nf < 2; ++nf) {
                bf16x8 bw = *(const bf16x8*)(Wbt + ((kb*4 + quad)*64 + cb0 + nf*16 + ln)*8);
                #pragma unroll
                for (int mf = 0; mf < 2; ++mf)
                    a1[mf][nf] = MFMA16(af[mf], bw, a1[mf][nf]);
            }
        }
        if (!isW21) {
            #pragma unroll
            for (int nf = 0; nf < 2; ++nf) {
                int o = cb0 + nf*16 + ln;
                float cb = bsel[o];
                #pragma unroll
                for (int mf = 0; mf < 2; ++mf)
                    #pragma unroll
                    for (int r = 0; r < 4; ++r) {
                        int t = mf*16 + quad*4 + r;
                        float v = a1[mf][nf][r] + cb; v = v > 0.f ? v : 0.f;
                        w11L[t*72 + o] = (__bf16)v;
                    }
            }
        } else {
            #pragma unroll
            for (int nf = 0; nf < 2; ++nf) {
                int o = cb0 + nf*16 + ln;
                float cb = bsel[o];
                #pragma unroll
                for (int mf = 0; mf < 2; ++mf) {
                    bf16x4 pk;
                    #pragma unroll
                    for (int r = 0; r < 4; ++r) {
                        float v = a1[mf][nf][r] + cb; v = v > 0.f ? v : 0.f;
                        pk[r] = (__bf16)v;
                    }
                    *(bf16x4*)(w21T + o*36 + mf*16 + quad*4) = pk;
                }
            }
        }
    }
    __syncthreads();

    // ---------- P2: w12 = w11@W12 + b12 (no relu); wave computes its 16 cols ----------
    {
        float c12 = b12[ob + ln];
        f32x4 a12c[2] = {};
        #pragma unroll
        for (int kb = 0; kb < 2; ++kb) {
            bf16x8 bw = *(const bf16x8*)(W12bt + ((kb*4 + quad)*64 + ob + ln)*8);
            #pragma unroll
            for (int mf = 0; mf < 2; ++mf) {
                bf16x8 af = *(const bf16x8*)(w11L + (mf*16 + ln)*72 + kb*32 + quad*8);
                a12c[mf] = MFMA16(af, bw, a12c[mf]);
            }
        }
        #pragma unroll
        for (int mf = 0; mf < 2; ++mf)
            #pragma unroll
            for (int r = 0; r < 4; ++r) {
                int t = mf*16 + quad*4 + r;
                w12L[t*72 + ob + ln] = (__bf16)(a12c[mf][r] + c12);
            }
    }
    __syncthreads();

    // w12 A-fragments: constant MFMA A-operand for the whole K-loop (and the
    // bias-block A directly). Full 64-k rows per token, 32 tokens/wave.
    bf16x8 a12[2][2];
    #pragma unroll
    for (int mf = 0; mf < 2; ++mf)
        #pragma unroll
        for (int sub = 0; sub < 2; ++sub)
            a12[mf][sub] = *(const bf16x8*)(w12L + (mf*16 + ln)*72 + sub*32 + quad*8);

    // ---------- P3: barrier-free K-loop, named VGPR double-buffer ----------
    // fragment (c, s): k8 = c*16 + s*4 + quad -> one contiguous 1 KB wave-load.
    const __bf16* Bw = Bt22 + ((long)wv * 520 + quad) * 128 + ln * 8;

    bf16x8 B0_0, B0_1, B0_2, B0_3;
    bf16x8 B1_0, B1_1, B1_2, B1_3;

    f32x4 acc[2] = {};
    LOADCH(B0, 0);
    #pragma unroll 1
    for (int cc = 0; cc < 32; cc += 2) {
        LOADCH(B1, cc + 1);
        COMPUTE(B0, cc);
        if (cc + 2 < 32) LOADCH(B0, cc + 2);
        COMPUTE(B1, cc + 1);
    }
    // bias rows: A = w12 directly, weight 1 (frags loaded now, buffers dead)
    {
        bf16x8 bb0 = *(const bf16x8*)(Bw + (512 + 0) * 128);
        bf16x8 bb1 = *(const bf16x8*)(Bw + (512 + 4) * 128);
        #pragma unroll
        for (int mf = 0; mf < 2; ++mf) {
            acc[mf] = MFMA16(a12[mf][0], bb0, acc[mf]);
            acc[mf] = MFMA16(a12[mf][1], bb1, acc[mf]);
        }
    }

    // ---------- P4: LayerNorm(64) + relu (cols split 16/wave -> LDS partials) ----------
    #pragma unroll
    for (int mf = 0; mf < 2; ++mf)
        #pragma unroll
        for (int r = 0; r < 4; ++r) {
            float v = acc[mf][r];
            float s1 = v, s2 = v*v;
            #pragma unroll
            for (int d = 1; d < 16; d <<= 1) {   // reduce this quad's 16 lanes
                s1 += __shfl_xor(s1, d, 64);
                s2 += __shfl_xor(s2, d, 64);
            }
            if (ln == 0) {
                int t = mf*16 + quad*4 + r;
                ps[t*4 + wv] = make_float2(s1, s2);
            }
        }
    __syncthreads();

    float gv = ln_g[ob + ln], bv = ln_b[ob + ln], b3v = b3[ob + ln];
    #pragma unroll
    for (int mf = 0; mf < 2; ++mf)
        #pragma unroll
        for (int r = 0; r < 4; ++r) {
            int t = mf*16 + quad*4 + r;
            float2 p0 = ps[t*4], p1 = ps[t*4 + 1], p2 = ps[t*4 + 2], p3 = ps[t*4 + 3];
            float mean = (p0.x + p1.x + p2.x + p3.x) * 0.015625f;
            float var  = (p0.y + p1.y + p2.y + p3.y) * 0.015625f - mean * mean;
            float inv  = rsqrtf(var + 1e-5f);
            float v = (acc[mf][r] - mean) * inv * gv + bv;
            v = v > 0.f ? v : 0.f;
            xL[t*72 + ob + ln] = (__bf16)v;
        }
    __syncthreads();

    // ---------- P5: out = x @ W3 + b3 (16 cols per wave, 32 tokens) ----------
    f32x4 a3[2] = {};
    #pragma unroll
    for (int kb = 0; kb < 2; ++kb) {
        bf16x8 bfr = *(const bf16x8*)(W3bt + ((kb*4 + quad)*64 + ob + ln)*8);
        #pragma unroll
        for (int mf = 0; mf < 2; ++mf) {
            bf16x8 af = *(const bf16x8*)(xL + (mf*16 + ln)*72 + kb*32 + quad*8);
            a3[mf] = MFMA16(af, bfr, a3[mf]);
        }
    }
    #pragma unroll
    for (int mf = 0; mf < 2; ++mf)
        #pragma unroll
        for (int r = 0; r < 4; ++r) {
            long t = tb + mf*16 + quad*4 + r;
            out[t*64 + ob + ln] = a3[mf][r] + b3v;
        }
}

extern "C" void kernel_launch(void* const* d_in, const int* in_sizes, int n_in,
                              void* d_out, int out_size, void* d_ws, size_t ws_size,
                              hipStream_t stream)
{
    const float* img  = (const float*)d_in[0];
    const float* loc  = (const float*)d_in[1];
    const float* W11  = (const float*)d_in[2];
    const float* b11  = (const float*)d_in[3];
    const float* W12  = (const float*)d_in[4];
    const float* b12  = (const float*)d_in[5];
    const float* W21  = (const float*)d_in[6];
    const float* b21  = (const float*)d_in[7];
    const float* W22  = (const float*)d_in[8];
    const float* b22  = (const float*)d_in[9];
    const float* ln_g = (const float*)d_in[10];
    const float* ln_b = (const float*)d_in[11];
    const float* W3   = (const float*)d_in[12];
    const float* b3   = (const float*)d_in[13];
    __bf16* ws = (__bf16*)d_ws;
    float*  o  = (float*)d_out;

    prep_kernel<<<71, 256, 0, stream>>>(W22, b22, W11, W21, W12, W3, ws);
    main_kernel<<<1024, 256, 0, stream>>>(img, loc, b11, b12, b21, ln_g, ln_b, b3, ws, o);
}